// Round 3
// baseline (232.538 us; speedup 1.0000x reference)
//
#include <hip/hip_runtime.h>
#include <hip/hip_bf16.h>
#include <math.h>

typedef __attribute__((ext_vector_type(4))) float f32x4;
typedef __attribute__((ext_vector_type(8))) short short8;

#define N_NODES 8192
#define KSEGS 8
#define WAVES 4
#define SEGLEN (N_NODES / KSEGS)   // 1024
#define WKSEG  (SEGLEN / WAVES)    // 256 columns per wave
#define LOG2E 1.44269504088896f

// f32 -> bf16 bits, round-to-nearest-even
__device__ __forceinline__ short f2bf(float x) {
    unsigned u = __float_as_uint(x);
    u += 0x7FFFu + ((u >> 16) & 1u);
    return (short)(u >> 16);
}

__device__ __forceinline__ float expneg(float s) {   // exp(-s)
    return __builtin_amdgcn_exp2f(-LOG2E * s);
}

// ---------------------------------------------------------------------------
// P1: h = x @ W1  [8192,500]@[500,64] with W1 staged in LDS (5 chunks of 100).
// 32 rows/block (8 per wave), 256 blocks. Also writes fsrc = exp(-h.a_src),
// edst = exp(-h.a_dst) for the factorized sigmoid.
// ---------------------------------------------------------------------------
#define P1_CHUNK 100
__global__ __launch_bounds__(256) void p1_kernel(
    const float* __restrict__ x, const float* __restrict__ W1,
    const float* __restrict__ a1, float* __restrict__ h,
    float* __restrict__ fsrc, float* __restrict__ edst)
{
    __shared__ float wtile[P1_CHUNK * 64];   // 25.6 KB
    const int lane = threadIdx.x & 63;
    const int w    = threadIdx.x >> 6;
    const int r0   = blockIdx.x * 32 + w * 8;

    float acc[8];
#pragma unroll
    for (int r = 0; r < 8; ++r) acc[r] = 0.f;

    for (int c = 0; c < 5; ++c) {
        const int kb = c * P1_CHUNK;
        __syncthreads();
        for (int idx = threadIdx.x; idx < P1_CHUNK * 64; idx += 256)
            wtile[idx] = W1[kb * 64 + idx];
        __syncthreads();
        for (int kk = 0; kk < P1_CHUNK; kk += 4) {
            float w0 = wtile[(kk + 0) * 64 + lane];
            float w1 = wtile[(kk + 1) * 64 + lane];
            float w2 = wtile[(kk + 2) * 64 + lane];
            float w3 = wtile[(kk + 3) * 64 + lane];
#pragma unroll
            for (int r = 0; r < 8; ++r) {
                f32x4 xv = *(const f32x4*)(x + (size_t)(r0 + r) * 500 + kb + kk);
                acc[r] = fmaf(xv[0], w0, acc[r]);
                acc[r] = fmaf(xv[1], w1, acc[r]);
                acc[r] = fmaf(xv[2], w2, acc[r]);
                acc[r] = fmaf(xv[3], w3, acc[r]);
            }
        }
    }
    float a_s = a1[lane], a_d = a1[64 + lane];
#pragma unroll
    for (int r = 0; r < 8; ++r) {
        h[(size_t)(r0 + r) * 64 + lane] = acc[r];
        float ps = acc[r] * a_s, pd = acc[r] * a_d;
        for (int off = 32; off > 0; off >>= 1) {
            ps += __shfl_down(ps, off); pd += __shfl_down(pd, off);
        }
        if (lane == 0) {
            fsrc[r0 + r] = expneg(ps);
            edst[r0 + r] = expneg(pd);
        }
    }
}

// ---------------------------------------------------------------------------
// Swizzle f32 matrix into bf16 B-fragment order:
// hB[kb][nb][lane][i] = bf16( h[kb*32 + (lane>>4)*8 + i][nb*16 + (lane&15)] )
// ---------------------------------------------------------------------------
__global__ __launch_bounds__(256) void swizzle_kernel(
    const float* __restrict__ h, short* __restrict__ hB,
    int nblk, int ncols, int total)
{
    int tid = blockIdx.x * 256 + threadIdx.x;
    if (tid >= total) return;
    int i  = tid & 7;
    int l  = (tid >> 3) & 63;
    int t2 = tid >> 9;
    int nb = t2 % nblk;
    int kb = t2 / nblk;
    int row = kb * 32 + (l >> 4) * 8 + i;
    int col = nb * 16 + (l & 15);
    hB[tid] = f2bf(h[(size_t)row * ncols + col]);
}

// ---------------------------------------------------------------------------
// Fused GAT layer pass. att = rcp(1 + F_i*E_j) * adj; accumulates att@h (MFMA)
// and sum(att^2) in one adj pass. Block = 4 waves on the same 16 rows, each
// wave a 256-col quarter of the block's 1024-col K segment; LDS reduction.
// One-step register prefetch (peeled last iteration) for load/compute overlap.
// ---------------------------------------------------------------------------
template <int NBLK>
__global__ __launch_bounds__(256) void gat_fused(
    const float* __restrict__ adj, const float* __restrict__ fsrc,
    const float* __restrict__ edst, const short* __restrict__ hB,
    float* __restrict__ outp, float* __restrict__ normp)
{
    __shared__ float red[WAVES][NBLK * 4][72];
    __shared__ float rednorm[WAVES][16];
    const int lane = threadIdx.x & 63;
    const int w    = threadIdx.x >> 6;
    const int rb   = blockIdx.x;
    const int seg  = blockIdx.y;
    const int r    = lane & 15;
    const int g    = lane >> 4;
    const int my_row = rb * 16 + r;
    const float F_i  = fsrc[my_row];
    const float* arow = adj + (size_t)my_row * N_NODES;

    f32x4 acc[NBLK];
#pragma unroll
    for (int nb = 0; nb < NBLK; ++nb) acc[nb] = (f32x4){0.f, 0.f, 0.f, 0.f};
    float nacc = 0.f;

    const int k0 = seg * SEGLEN + w * WKSEG;
    const float* ap = arow + k0 + g * 8;
    const float* ep = edst + k0 + g * 8;

    auto compute = [&](int kk, f32x4 a0, f32x4 a1v, f32x4 e0, f32x4 e1) {
        short8 af;
#pragma unroll
        for (int i = 0; i < 4; ++i) {
            float e   = __builtin_amdgcn_rcpf(fmaf(F_i, e0[i], 1.0f));
            float att = e * a0[i];
            nacc = fmaf(att, att, nacc);
            af[i] = f2bf(att);
        }
#pragma unroll
        for (int i = 0; i < 4; ++i) {
            float e   = __builtin_amdgcn_rcpf(fmaf(F_i, e1[i], 1.0f));
            float att = e * a1v[i];
            nacc = fmaf(att, att, nacc);
            af[4 + i] = f2bf(att);
        }
        const int kb = (k0 + kk) >> 5;
#pragma unroll
        for (int nb = 0; nb < NBLK; ++nb) {
            short8 bf = *(const short8*)(hB + ((size_t)(kb * NBLK + nb) * 64 + lane) * 8);
            acc[nb] = __builtin_amdgcn_mfma_f32_16x16x32_bf16(af, bf, acc[nb], 0, 0, 0);
        }
    };

    f32x4 a0c = *(const f32x4*)(ap);
    f32x4 a1c = *(const f32x4*)(ap + 4);
    f32x4 e0c = *(const f32x4*)(ep);
    f32x4 e1c = *(const f32x4*)(ep + 4);
    for (int kk = 0; kk < WKSEG - 32; kk += 32) {
        f32x4 a0n = *(const f32x4*)(ap + kk + 32);
        f32x4 a1n = *(const f32x4*)(ap + kk + 36);
        f32x4 e0n = *(const f32x4*)(ep + kk + 32);
        f32x4 e1n = *(const f32x4*)(ep + kk + 36);
        compute(kk, a0c, a1c, e0c, e1c);
        a0c = a0n; a1c = a1n; e0c = e0n; e1c = e1n;
    }
    compute(WKSEG - 32, a0c, a1c, e0c, e1c);

    nacc += __shfl_xor(nacc, 16);
    nacc += __shfl_xor(nacc, 32);

#pragma unroll
    for (int nb = 0; nb < NBLK; ++nb)
#pragma unroll
        for (int rr = 0; rr < 4; ++rr)
            red[w][nb * 4 + rr][lane] = acc[nb][rr];
    if (lane < 16) rednorm[w][lane] = nacc;
    __syncthreads();

    constexpr int F = NBLK * 16;
#pragma unroll
    for (int j = 0; j < NBLK; ++j) {
        int o   = threadIdx.x + 256 * j;
        int row = o / F;
        int f   = o % F;
        int gg = row >> 2, rr = row & 3, c = f & 15, nb = f >> 4;
        float s = red[0][nb * 4 + rr][gg * 16 + c]
                + red[1][nb * 4 + rr][gg * 16 + c]
                + red[2][nb * 4 + rr][gg * 16 + c]
                + red[3][nb * 4 + rr][gg * 16 + c];
        outp[((size_t)seg * N_NODES + rb * 16 + row) * F + f] = s;
    }
    if (threadIdx.x < 16) {
        float n = rednorm[0][threadIdx.x] + rednorm[1][threadIdx.x]
                + rednorm[2][threadIdx.x] + rednorm[3][threadIdx.x];
        normp[(size_t)seg * N_NODES + rb * 16 + threadIdx.x] = n;
    }
}

// ---------------------------------------------------------------------------
// R1: h1[i][f] = sum_seg outp1 / (sqrt(sum_seg normp1) + 1e-10)
// ---------------------------------------------------------------------------
__global__ __launch_bounds__(256) void r1_kernel(
    const float* __restrict__ outp, const float* __restrict__ normp,
    float* __restrict__ h1)
{
    int tid = blockIdx.x * 256 + threadIdx.x;
    int i = tid >> 6, f = tid & 63;
    float s = 0.f, n = 0.f;
#pragma unroll
    for (int sg = 0; sg < KSEGS; ++sg) {
        s += outp[((size_t)sg * N_NODES + i) * 64 + f];
        n += normp[sg * N_NODES + i];
    }
    h1[tid] = s / (sqrtf(n) + 1e-10f);
}

// ---------------------------------------------------------------------------
// P2: z = h1 @ W2 (padded to 16 cols), fsrc2/edst2 = exp(-z . a2 halves)
// ---------------------------------------------------------------------------
__global__ __launch_bounds__(256) void p2_kernel(
    const float* __restrict__ h1, const float* __restrict__ W2,
    const float* __restrict__ a2, float* __restrict__ z,
    float* __restrict__ fsrc2, float* __restrict__ edst2)
{
    int i = blockIdx.x * 256 + threadIdx.x;
    if (i >= N_NODES) return;
    float zz[10];
#pragma unroll
    for (int c = 0; c < 10; ++c) zz[c] = 0.f;
    for (int f = 0; f < 64; ++f) {
        float hv = h1[(size_t)i * 64 + f];
#pragma unroll
        for (int c = 0; c < 10; ++c) zz[c] = fmaf(hv, W2[f * 10 + c], zz[c]);
    }
    float s1 = 0.f, s2 = 0.f;
#pragma unroll
    for (int c = 0; c < 10; ++c) {
        s1 = fmaf(zz[c], a2[c], s1);
        s2 = fmaf(zz[c], a2[10 + c], s2);
        z[(size_t)i * 16 + c] = zz[c];
    }
#pragma unroll
    for (int c = 10; c < 16; ++c) z[(size_t)i * 16 + c] = 0.f;
    fsrc2[i] = expneg(s1);
    edst2[i] = expneg(s2);
}

// ---------------------------------------------------------------------------
// R2: h2 = partials/norm, then log_softmax over 10 classes -> d_out
// ---------------------------------------------------------------------------
__global__ __launch_bounds__(256) void r2_kernel(
    const float* __restrict__ outp, const float* __restrict__ normp,
    float* __restrict__ out)
{
    int i = blockIdx.x * 256 + threadIdx.x;
    if (i >= N_NODES) return;
    float n = 0.f;
#pragma unroll
    for (int sg = 0; sg < KSEGS; ++sg) n += normp[sg * N_NODES + i];
    float inv = 1.0f / (sqrtf(n) + 1e-10f);
    float v[10];
    float m = -1e30f;
#pragma unroll
    for (int c = 0; c < 10; ++c) {
        float s = 0.f;
#pragma unroll
        for (int sg = 0; sg < KSEGS; ++sg)
            s += outp[((size_t)sg * N_NODES + i) * 16 + c];
        v[c] = s * inv;
        m = fmaxf(m, v[c]);
    }
    float es = 0.f;
#pragma unroll
    for (int c = 0; c < 10; ++c) es += expf(v[c] - m);
    float lse = m + logf(es);
#pragma unroll
    for (int c = 0; c < 10; ++c) out[(size_t)i * 10 + c] = v[c] - lse;
}

extern "C" void kernel_launch(void* const* d_in, const int* in_sizes, int n_in,
                              void* d_out, int out_size, void* d_ws, size_t ws_size,
                              hipStream_t stream)
{
    const float* x   = (const float*)d_in[0];
    const float* adj = (const float*)d_in[1];
    const float* W1  = (const float*)d_in[2];
    const float* a1  = (const float*)d_in[3];
    const float* W2  = (const float*)d_in[4];
    const float* a2  = (const float*)d_in[5];
    float* out = (float*)d_out;

    char* ws = (char*)d_ws;
    size_t off = 0;
    auto alloc = [&](size_t bytes) -> void* {
        void* p = ws + off;
        off += (bytes + 255) & ~(size_t)255;
        return p;
    };
    float* h      = (float*)alloc((size_t)N_NODES * 64 * 4);
    float* fsrc1  = (float*)alloc((size_t)N_NODES * 4);
    float* edst1  = (float*)alloc((size_t)N_NODES * 4);
    short* hB1    = (short*)alloc((size_t)N_NODES * 64 * 2);
    float* outp1  = (float*)alloc((size_t)KSEGS * N_NODES * 64 * 4);
    float* normp1 = (float*)alloc((size_t)KSEGS * N_NODES * 4);
    float* h1     = (float*)alloc((size_t)N_NODES * 64 * 4);
    float* z      = (float*)alloc((size_t)N_NODES * 16 * 4);
    float* fsrc2  = (float*)alloc((size_t)N_NODES * 4);
    float* edst2  = (float*)alloc((size_t)N_NODES * 4);
    short* zB     = (short*)alloc((size_t)N_NODES * 16 * 2);
    float* outp2  = (float*)alloc((size_t)KSEGS * N_NODES * 16 * 4);
    float* normp2 = (float*)alloc((size_t)KSEGS * N_NODES * 4);

    hipLaunchKernelGGL(p1_kernel, dim3(N_NODES / 32), dim3(256), 0, stream,
                       x, W1, a1, h, fsrc1, edst1);
    hipLaunchKernelGGL(swizzle_kernel, dim3(2048), dim3(256), 0, stream,
                       h, hB1, 4, 64, N_NODES * 64);
    hipLaunchKernelGGL((gat_fused<4>), dim3(N_NODES / 16, KSEGS), dim3(256), 0, stream,
                       adj, fsrc1, edst1, hB1, outp1, normp1);
    hipLaunchKernelGGL(r1_kernel, dim3(2048), dim3(256), 0, stream,
                       outp1, normp1, h1);
    hipLaunchKernelGGL(p2_kernel, dim3(32), dim3(256), 0, stream,
                       h1, W2, a2, z, fsrc2, edst2);
    hipLaunchKernelGGL(swizzle_kernel, dim3(512), dim3(256), 0, stream,
                       z, zB, 1, 16, N_NODES * 16);
    hipLaunchKernelGGL((gat_fused<1>), dim3(N_NODES / 16, KSEGS), dim3(256), 0, stream,
                       adj, fsrc2, edst2, zB, outp2, normp2);
    hipLaunchKernelGGL(r2_kernel, dim3(32), dim3(256), 0, stream,
                       outp2, normp2, out);
}

// Round 4
// 227.546 us; speedup vs baseline: 1.0219x; 1.0219x over previous
//
#include <hip/hip_runtime.h>
#include <hip/hip_bf16.h>
#include <math.h>

typedef __attribute__((ext_vector_type(4))) float f32x4;
typedef __attribute__((ext_vector_type(8))) short short8;

#define N_NODES 8192
#define KSEGS 4
#define SEG    (N_NODES / KSEGS)    // 2048 cols per block
#define CHUNK  256                  // cols per staged chunk
#define NCH    (SEG / CHUNK)        // 8 chunks
#define ROWS   16
#define LOG2E  1.44269504088896f

// async global->LDS, 16B per lane; dest is wave-uniform base (+lane*16 by HW)
#define GLD16(gptr, lptr)                                                     \
    __builtin_amdgcn_global_load_lds(                                         \
        (const __attribute__((address_space(1))) void*)(gptr),                \
        (__attribute__((address_space(3))) void*)(lptr), 16, 0, 0)

// f32 -> bf16 bits, round-to-nearest-even
__device__ __forceinline__ short f2bf(float x) {
    unsigned u = __float_as_uint(x);
    u += 0x7FFFu + ((u >> 16) & 1u);
    return (short)(u >> 16);
}
__device__ __forceinline__ float bf2f(short s) {
    return __uint_as_float(((unsigned)(unsigned short)s) << 16);
}
__device__ __forceinline__ float expneg(float s) {   // exp(-s)
    return __builtin_amdgcn_exp2f(-LOG2E * s);
}

// ---------------------------------------------------------------------------
// P1: h = x @ W1  [8192,500]@[500,64] with W1 staged in LDS.
// Writes fsrc = exp(-h.a_src), edst = exp(-h.a_dst).
// ---------------------------------------------------------------------------
#define P1_CHUNK 100
__global__ __launch_bounds__(256) void p1_kernel(
    const float* __restrict__ x, const float* __restrict__ W1,
    const float* __restrict__ a1, float* __restrict__ h,
    float* __restrict__ fsrc, float* __restrict__ edst)
{
    __shared__ float wtile[P1_CHUNK * 64];
    const int lane = threadIdx.x & 63;
    const int w    = threadIdx.x >> 6;
    const int r0   = blockIdx.x * 32 + w * 8;

    float acc[8];
#pragma unroll
    for (int r = 0; r < 8; ++r) acc[r] = 0.f;

    for (int c = 0; c < 5; ++c) {
        const int kb = c * P1_CHUNK;
        __syncthreads();
        for (int idx = threadIdx.x; idx < P1_CHUNK * 64; idx += 256)
            wtile[idx] = W1[kb * 64 + idx];
        __syncthreads();
        for (int kk = 0; kk < P1_CHUNK; kk += 4) {
            float w0 = wtile[(kk + 0) * 64 + lane];
            float w1 = wtile[(kk + 1) * 64 + lane];
            float w2 = wtile[(kk + 2) * 64 + lane];
            float w3 = wtile[(kk + 3) * 64 + lane];
#pragma unroll
            for (int r = 0; r < 8; ++r) {
                f32x4 xv = *(const f32x4*)(x + (size_t)(r0 + r) * 500 + kb + kk);
                acc[r] = fmaf(xv[0], w0, acc[r]);
                acc[r] = fmaf(xv[1], w1, acc[r]);
                acc[r] = fmaf(xv[2], w2, acc[r]);
                acc[r] = fmaf(xv[3], w3, acc[r]);
            }
        }
    }
    float a_s = a1[lane], a_d = a1[64 + lane];
#pragma unroll
    for (int r = 0; r < 8; ++r) {
        h[(size_t)(r0 + r) * 64 + lane] = acc[r];
        float ps = acc[r] * a_s, pd = acc[r] * a_d;
        for (int off = 32; off > 0; off >>= 1) {
            ps += __shfl_down(ps, off); pd += __shfl_down(pd, off);
        }
        if (lane == 0) {
            fsrc[r0 + r] = expneg(ps);
            edst[r0 + r] = expneg(pd);
        }
    }
}

// ---------------------------------------------------------------------------
// Swizzle f32 matrix into bf16 B-fragment order:
// hB[kb][nb][lane][i] = bf16( h[kb*32 + (lane>>4)*8 + i][nb*16 + (lane&15)] )
// ---------------------------------------------------------------------------
__global__ __launch_bounds__(256) void swizzle_kernel(
    const float* __restrict__ h, short* __restrict__ hB,
    int nblk, int ncols, int total)
{
    int tid = blockIdx.x * 256 + threadIdx.x;
    if (tid >= total) return;
    int i  = tid & 7;
    int l  = (tid >> 3) & 63;
    int t2 = tid >> 9;
    int nb = t2 % nblk;
    int kb = t2 / nblk;
    int row = kb * 32 + (l >> 4) * 8 + i;
    int col = nb * 16 + (l & 15);
    hB[tid] = f2bf(h[(size_t)row * ncols + col]);
}

// ---------------------------------------------------------------------------
// GAT layer 1: async-LDS-staged adj (f32), att = adj * rcp(1+F_i*E_j),
// MFMA vs hB, per-row att^2, AND writes adjB = bf16(adj) for layer 2.
// Block: 16 rows x 2048 cols in 8 double-buffered 256-col chunks.
// 4 waves split each chunk's 8 k-steps (kk = w, w+4). LDS reduce at end.
// ---------------------------------------------------------------------------
__global__ __launch_bounds__(256) void gat1_kernel(
    const float* __restrict__ adj, const float* __restrict__ fsrc,
    const float* __restrict__ edst, const short* __restrict__ hB,
    short* __restrict__ adjB, float* __restrict__ outp,
    float* __restrict__ normp)
{
    __shared__ float bufA[2][ROWS * CHUNK];   // 2 x 16KB
    __shared__ float ebuf[2][CHUNK];          // 2 x 1KB
    __shared__ float red[4][16][72];
    __shared__ float rednorm[4][16];

    const int lane = threadIdx.x & 63;
    const int w    = threadIdx.x >> 6;
    const int rb   = blockIdx.x;
    const int seg  = blockIdx.y;
    const int r    = lane & 15;
    const int g    = lane >> 4;
    const int my_row = rb * ROWS + r;
    const float F_i  = fsrc[my_row];

    f32x4 acc[4];
#pragma unroll
    for (int nb = 0; nb < 4; ++nb) acc[nb] = (f32x4){0.f, 0.f, 0.f, 0.f};
    float nacc = 0.f;

    auto fill = [&](int c, int cb) {
        const size_t colf = (size_t)seg * SEG + c * CHUNK;
#pragma unroll
        for (int i = 0; i < 4; ++i) {
            const int j = w * 4 + i;   // row within tile
            const float* gsrc = adj + ((size_t)rb * ROWS + j) * N_NODES + colf
                              + (((lane * 16) ^ ((j & 7) << 4)) >> 2);
            GLD16(gsrc, &bufA[cb][j * 256]);
        }
        if (w == 0) {
            const float* gsrc = edst + colf + lane * 4;
            GLD16(gsrc, &ebuf[cb][0]);
        }
    };

    fill(0, 0);
    __syncthreads();

    for (int c = 0; c < NCH; ++c) {
        const int cb = c & 1;
        if (c + 1 < NCH) fill(c + 1, cb ^ 1);
        const int colbase = seg * SEG + c * CHUNK;
#pragma unroll
        for (int i = 0; i < 2; ++i) {
            const int kk = w + i * 4;          // this wave's k-steps
            const int q0 = kk * 128 + g * 32;  // byte offset within row
            const int xo = (r & 7) << 4;
            const char* rowp = (const char*)&bufA[cb][r * 256];
            f32x4 a0 = *(const f32x4*)(rowp + ((q0) ^ xo));
            f32x4 a1 = *(const f32x4*)(rowp + ((q0 + 16) ^ xo));
            f32x4 e0 = *(const f32x4*)&ebuf[cb][kk * 32 + g * 8];
            f32x4 e1 = *(const f32x4*)&ebuf[cb][kk * 32 + g * 8 + 4];
            short8 af, ab;
#pragma unroll
            for (int t = 0; t < 4; ++t) {
                float sg  = __builtin_amdgcn_rcpf(fmaf(F_i, e0[t], 1.0f));
                float att = sg * a0[t];
                nacc = fmaf(att, att, nacc);
                af[t] = f2bf(att);
                ab[t] = f2bf(a0[t]);
            }
#pragma unroll
            for (int t = 0; t < 4; ++t) {
                float sg  = __builtin_amdgcn_rcpf(fmaf(F_i, e1[t], 1.0f));
                float att = sg * a1[t];
                nacc = fmaf(att, att, nacc);
                af[4 + t] = f2bf(att);
                ab[4 + t] = f2bf(a1[t]);
            }
            // bf16 adj copy for layer 2
            *(short8*)(adjB + (size_t)my_row * N_NODES + colbase + kk * 32 + g * 8) = ab;
            const int kb = (colbase + kk * 32) >> 5;
#pragma unroll
            for (int nb = 0; nb < 4; ++nb) {
                short8 bf = *(const short8*)(hB + ((size_t)(kb * 4 + nb) * 64 + lane) * 8);
                acc[nb] = __builtin_amdgcn_mfma_f32_16x16x32_bf16(af, bf, acc[nb], 0, 0, 0);
            }
        }
        __syncthreads();
    }

    nacc += __shfl_xor(nacc, 16);
    nacc += __shfl_xor(nacc, 32);

#pragma unroll
    for (int nb = 0; nb < 4; ++nb)
#pragma unroll
        for (int rr = 0; rr < 4; ++rr)
            red[w][nb * 4 + rr][lane] = acc[nb][rr];
    if (lane < 16) rednorm[w][lane] = nacc;
    __syncthreads();

#pragma unroll
    for (int j = 0; j < 4; ++j) {
        int o   = threadIdx.x + 256 * j;
        int row = o >> 6;          // /64
        int f   = o & 63;
        int gg = row >> 2, rr = row & 3, cc = f & 15, nb = f >> 4;
        float s = red[0][nb * 4 + rr][gg * 16 + cc]
                + red[1][nb * 4 + rr][gg * 16 + cc]
                + red[2][nb * 4 + rr][gg * 16 + cc]
                + red[3][nb * 4 + rr][gg * 16 + cc];
        outp[((size_t)seg * N_NODES + rb * ROWS + row) * 64 + f] = s;
    }
    if (threadIdx.x < 16) {
        float n = rednorm[0][threadIdx.x] + rednorm[1][threadIdx.x]
                + rednorm[2][threadIdx.x] + rednorm[3][threadIdx.x];
        normp[(size_t)seg * N_NODES + rb * ROWS + threadIdx.x] = n;
    }
}

// ---------------------------------------------------------------------------
// GAT layer 2: same structure, reads bf16 adjB (134MB, L3-resident), NBLK=1.
// ---------------------------------------------------------------------------
__global__ __launch_bounds__(256) void gat2_kernel(
    const short* __restrict__ adjB, const float* __restrict__ fsrc,
    const float* __restrict__ edst, const short* __restrict__ zB,
    float* __restrict__ outp, float* __restrict__ normp)
{
    __shared__ short bufB[2][ROWS * CHUNK];   // 2 x 8KB
    __shared__ float ebuf[2][CHUNK];
    __shared__ float red[4][4][72];
    __shared__ float rednorm[4][16];

    const int lane = threadIdx.x & 63;
    const int w    = threadIdx.x >> 6;
    const int rb   = blockIdx.x;
    const int seg  = blockIdx.y;
    const int r    = lane & 15;
    const int g    = lane >> 4;
    const int my_row = rb * ROWS + r;
    const float F_i  = fsrc[my_row];

    f32x4 acc = (f32x4){0.f, 0.f, 0.f, 0.f};
    float nacc = 0.f;

    auto fill = [&](int c, int cb) {
        const size_t cols = (size_t)seg * SEG + c * CHUNK;   // col idx (shorts)
#pragma unroll
        for (int i = 0; i < 2; ++i) {
            const int j   = w * 2 + i;               // pair index 0..7
            const int row = 2 * j + (lane >> 5);     // tile row 0..15
            const int q   = ((lane & 31) * 16) ^ ((row & 7) << 4);
            const short* gsrc = adjB + ((size_t)rb * ROWS + row) * N_NODES + cols
                              + (q >> 1);
            GLD16(gsrc, &bufB[cb][j * 512]);
        }
        if (w == 0) {
            const float* gsrc = edst + cols + lane * 4;
            GLD16(gsrc, &ebuf[cb][0]);
        }
    };

    fill(0, 0);
    __syncthreads();

    for (int c = 0; c < NCH; ++c) {
        const int cb = c & 1;
        if (c + 1 < NCH) fill(c + 1, cb ^ 1);
        const int colbase = seg * SEG + c * CHUNK;
#pragma unroll
        for (int i = 0; i < 2; ++i) {
            const int kk = w + i * 4;
            const int xo = (r & 7) << 4;
            const char* base = (const char*)&bufB[cb][0];
            short8 av = *(const short8*)(base + r * 512 + ((kk * 64 + g * 16) ^ xo));
            f32x4 e0 = *(const f32x4*)&ebuf[cb][kk * 32 + g * 8];
            f32x4 e1 = *(const f32x4*)&ebuf[cb][kk * 32 + g * 8 + 4];
            short8 af;
#pragma unroll
            for (int t = 0; t < 4; ++t) {
                float a   = bf2f(av[t]);
                float sg  = __builtin_amdgcn_rcpf(fmaf(F_i, e0[t], 1.0f));
                float att = sg * a;
                nacc = fmaf(att, att, nacc);
                af[t] = f2bf(att);
            }
#pragma unroll
            for (int t = 0; t < 4; ++t) {
                float a   = bf2f(av[4 + t]);
                float sg  = __builtin_amdgcn_rcpf(fmaf(F_i, e1[t], 1.0f));
                float att = sg * a;
                nacc = fmaf(att, att, nacc);
                af[4 + t] = f2bf(att);
            }
            const int kb = (colbase + kk * 32) >> 5;
            short8 bf = *(const short8*)(zB + ((size_t)kb * 64 + lane) * 8);
            acc = __builtin_amdgcn_mfma_f32_16x16x32_bf16(af, bf, acc, 0, 0, 0);
        }
        __syncthreads();
    }

    nacc += __shfl_xor(nacc, 16);
    nacc += __shfl_xor(nacc, 32);

#pragma unroll
    for (int rr = 0; rr < 4; ++rr)
        red[w][rr][lane] = acc[rr];
    if (lane < 16) rednorm[w][lane] = nacc;
    __syncthreads();

    {
        int o   = threadIdx.x;
        int row = o >> 4;
        int f   = o & 15;
        int gg = row >> 2, rr = row & 3;
        float s = red[0][rr][gg * 16 + f] + red[1][rr][gg * 16 + f]
                + red[2][rr][gg * 16 + f] + red[3][rr][gg * 16 + f];
        outp[((size_t)seg * N_NODES + rb * ROWS + row) * 16 + f] = s;
    }
    if (threadIdx.x < 16) {
        float n = rednorm[0][threadIdx.x] + rednorm[1][threadIdx.x]
                + rednorm[2][threadIdx.x] + rednorm[3][threadIdx.x];
        normp[(size_t)seg * N_NODES + rb * ROWS + threadIdx.x] = n;
    }
}

// ---------------------------------------------------------------------------
// R1: h1[i][f] = sum_seg outp1 / (sqrt(sum_seg normp1) + 1e-10)
// ---------------------------------------------------------------------------
__global__ __launch_bounds__(256) void r1_kernel(
    const float* __restrict__ outp, const float* __restrict__ normp,
    float* __restrict__ h1)
{
    int tid = blockIdx.x * 256 + threadIdx.x;
    int i = tid >> 6, f = tid & 63;
    float s = 0.f, n = 0.f;
#pragma unroll
    for (int sg = 0; sg < KSEGS; ++sg) {
        s += outp[((size_t)sg * N_NODES + i) * 64 + f];
        n += normp[sg * N_NODES + i];
    }
    h1[tid] = s / (sqrtf(n) + 1e-10f);
}

// ---------------------------------------------------------------------------
// P2: z = h1 @ W2 (padded to 16 cols), fsrc2/edst2 = exp(-z . a2 halves)
// ---------------------------------------------------------------------------
__global__ __launch_bounds__(256) void p2_kernel(
    const float* __restrict__ h1, const float* __restrict__ W2,
    const float* __restrict__ a2, float* __restrict__ z,
    float* __restrict__ fsrc2, float* __restrict__ edst2)
{
    int i = blockIdx.x * 256 + threadIdx.x;
    if (i >= N_NODES) return;
    float zz[10];
#pragma unroll
    for (int c = 0; c < 10; ++c) zz[c] = 0.f;
    for (int f = 0; f < 64; ++f) {
        float hv = h1[(size_t)i * 64 + f];
#pragma unroll
        for (int c = 0; c < 10; ++c) zz[c] = fmaf(hv, W2[f * 10 + c], zz[c]);
    }
    float s1 = 0.f, s2 = 0.f;
#pragma unroll
    for (int c = 0; c < 10; ++c) {
        s1 = fmaf(zz[c], a2[c], s1);
        s2 = fmaf(zz[c], a2[10 + c], s2);
        z[(size_t)i * 16 + c] = zz[c];
    }
#pragma unroll
    for (int c = 10; c < 16; ++c) z[(size_t)i * 16 + c] = 0.f;
    fsrc2[i] = expneg(s1);
    edst2[i] = expneg(s2);
}

// ---------------------------------------------------------------------------
// R2: h2 = partials/norm, then log_softmax over 10 classes -> d_out
// ---------------------------------------------------------------------------
__global__ __launch_bounds__(256) void r2_kernel(
    const float* __restrict__ outp, const float* __restrict__ normp,
    float* __restrict__ out)
{
    int i = blockIdx.x * 256 + threadIdx.x;
    if (i >= N_NODES) return;
    float n = 0.f;
#pragma unroll
    for (int sg = 0; sg < KSEGS; ++sg) n += normp[sg * N_NODES + i];
    float inv = 1.0f / (sqrtf(n) + 1e-10f);
    float v[10];
    float m = -1e30f;
#pragma unroll
    for (int c = 0; c < 10; ++c) {
        float s = 0.f;
#pragma unroll
        for (int sg = 0; sg < KSEGS; ++sg)
            s += outp[((size_t)sg * N_NODES + i) * 16 + c];
        v[c] = s * inv;
        m = fmaxf(m, v[c]);
    }
    float es = 0.f;
#pragma unroll
    for (int c = 0; c < 10; ++c) es += expf(v[c] - m);
    float lse = m + logf(es);
#pragma unroll
    for (int c = 0; c < 10; ++c) out[(size_t)i * 10 + c] = v[c] - lse;
}

extern "C" void kernel_launch(void* const* d_in, const int* in_sizes, int n_in,
                              void* d_out, int out_size, void* d_ws, size_t ws_size,
                              hipStream_t stream)
{
    const float* x   = (const float*)d_in[0];
    const float* adj = (const float*)d_in[1];
    const float* W1  = (const float*)d_in[2];
    const float* a1  = (const float*)d_in[3];
    const float* W2  = (const float*)d_in[4];
    const float* a2  = (const float*)d_in[5];
    float* out = (float*)d_out;

    char* ws = (char*)d_ws;
    size_t off = 0;
    auto alloc = [&](size_t bytes) -> void* {
        void* p = ws + off;
        off += (bytes + 255) & ~(size_t)255;
        return p;
    };
    short* adjB   = (short*)alloc((size_t)N_NODES * N_NODES * 2);   // 134MB
    float* h      = (float*)alloc((size_t)N_NODES * 64 * 4);
    float* fsrc1  = (float*)alloc((size_t)N_NODES * 4);
    float* edst1  = (float*)alloc((size_t)N_NODES * 4);
    short* hB1    = (short*)alloc((size_t)N_NODES * 64 * 2);
    float* outp1  = (float*)alloc((size_t)KSEGS * N_NODES * 64 * 4);
    float* normp1 = (float*)alloc((size_t)KSEGS * N_NODES * 4);
    float* h1     = (float*)alloc((size_t)N_NODES * 64 * 4);
    float* z      = (float*)alloc((size_t)N_NODES * 16 * 4);
    float* fsrc2  = (float*)alloc((size_t)N_NODES * 4);
    float* edst2  = (float*)alloc((size_t)N_NODES * 4);
    short* zB     = (short*)alloc((size_t)N_NODES * 16 * 2);
    float* outp2  = (float*)alloc((size_t)KSEGS * N_NODES * 16 * 4);
    float* normp2 = (float*)alloc((size_t)KSEGS * N_NODES * 4);

    hipLaunchKernelGGL(p1_kernel, dim3(N_NODES / 32), dim3(256), 0, stream,
                       x, W1, a1, h, fsrc1, edst1);
    hipLaunchKernelGGL(swizzle_kernel, dim3(2048), dim3(256), 0, stream,
                       h, hB1, 4, 64, N_NODES * 64);
    hipLaunchKernelGGL(gat1_kernel, dim3(N_NODES / ROWS, KSEGS), dim3(256), 0, stream,
                       adj, fsrc1, edst1, hB1, adjB, outp1, normp1);
    hipLaunchKernelGGL(r1_kernel, dim3(2048), dim3(256), 0, stream,
                       outp1, normp1, h1);
    hipLaunchKernelGGL(p2_kernel, dim3(32), dim3(256), 0, stream,
                       h1, W2, a2, z, fsrc2, edst2);
    hipLaunchKernelGGL(swizzle_kernel, dim3(512), dim3(256), 0, stream,
                       z, zB, 1, 16, N_NODES * 16);
    hipLaunchKernelGGL(gat2_kernel, dim3(N_NODES / ROWS, KSEGS), dim3(256), 0, stream,
                       adjB, fsrc2, edst2, zB, outp2, normp2);
    hipLaunchKernelGGL(r2_kernel, dim3(32), dim3(256), 0, stream,
                       outp2, normp2, out);
}